// Round 2
// baseline (268.131 us; speedup 1.0000x reference)
//
#include <hip/hip_runtime.h>
#include <hip/hip_bf16.h>

// Problem: CausalSelfAttention  B=2, T=2048, C=1024, H=16, D=64
// Round 14: GEMM 2-phase double-buffering.
// qkv_qk was the top kernel (68us, MfmaUtil 31%) in the m97-style
// stage->barrier->compute->barrier loop: gload_lds drained by the very next
// barrier, zero load/compute overlap (the known ~900TF structural ceiling;
// we were at 757TF eff). This round:
// (1) T3 minimum 2-phase on qkv_qk/qkv_v/proj: LDS double-buffer, stage
//     tile k+1 BEFORE compute of tile k, ONE barrier per K-step. Loads fly
//     under the MFMA phase. qkv_qk LDS 32->64KB (still 2 blocks/CU),
//     qkv_v/proj 16->32KB.
// (2) T1 bijective XCD swizzle on the GEMM grids (512%8==0, 256%8==0):
//     contiguous m-panels per XCD -> A-panel L2 reuse (FETCH was 70MB vs
//     24MB ideal).
// attn_mfma (paired q-tiles, XOR-swizzle, defer-max) unchanged from R13.
// ws (62 MB): Qh 8|Ql 8|Kh 8|Kl 8|xh 8(->Yb)|xl 8(->VT)|WaTh 6|WaTl 6|WpT 2

#define B_  2
#define T_  2048
#define C_  1024
#define H_  16
#define D_  64
#define M_  (B_ * T_)      // 4096
#define N3_ (3 * C_)       // 3072

typedef __attribute__((ext_vector_type(8))) short s16x8;
typedef __attribute__((ext_vector_type(4))) short s16x4;
typedef __attribute__((ext_vector_type(4))) float f32x4;

typedef const __attribute__((address_space(1))) unsigned int gu32_t;
typedef __attribute__((address_space(3))) unsigned int lu32_t;

#define MFMA16(a, b, c) __builtin_amdgcn_mfma_f32_16x16x32_bf16(a, b, c, 0, 0, 0)

__device__ __forceinline__ void gload_lds16(const short* g, short* l) {
    __builtin_amdgcn_global_load_lds((gu32_t*)g, (lu32_t*)l, 16, 0, 0);
}

__device__ __forceinline__ float b2f(unsigned short u) {
    return __uint_as_float(((unsigned)u) << 16);
}
__device__ __forceinline__ unsigned short f2b(float f) {   // RNE bf16 round
    unsigned u = __float_as_uint(f);
    return (unsigned short)((u + 0x7FFFu + ((u >> 16) & 1u)) >> 16);
}
__device__ __forceinline__ float fexp2(float x) {
#if __has_builtin(__builtin_amdgcn_exp2f)
    return __builtin_amdgcn_exp2f(x);
#else
    return exp2f(x);
#endif
}

// ---------------------------------------------------------------------------
// fp32 -> (hi, lo) bf16 split. n multiple of 2048.
// ---------------------------------------------------------------------------
__global__ __launch_bounds__(256) void cvt_split(
    const float* __restrict__ in, short* __restrict__ oh, short* __restrict__ ol, int n)
{
    int i = (blockIdx.x * 256 + threadIdx.x) * 8;
    if (i >= n) return;
    float4 a = *(const float4*)&in[i];
    float4 b = *(const float4*)&in[i + 4];
    float v[8] = {a.x, a.y, a.z, a.w, b.x, b.y, b.z, b.w};
    s16x8 h, l;
    #pragma unroll
    for (int j = 0; j < 8; j++) {
        unsigned short hb = f2b(v[j]);
        h[j] = (short)hb;
        l[j] = (short)f2b(v[j] - b2f(hb));
    }
    *(s16x8*)&oh[i] = h;
    *(s16x8*)&ol[i] = l;
}

// ---------------------------------------------------------------------------
// fp32 [R,Cn] -> (hi,lo) bf16 [Cn,R] transpose+split. grid (Cn/64, R/64).
// ---------------------------------------------------------------------------
__global__ __launch_bounds__(256) void cvtT_split(
    const float* __restrict__ in, short* __restrict__ oh, short* __restrict__ ol,
    int R, int Cn)
{
    __shared__ short th[64][80];
    __shared__ short tl[64][80];
    const int tid = threadIdx.x;
    const int k0 = blockIdx.y * 64;
    const int n0 = blockIdx.x * 64;
    {
        int rl = tid >> 4, cl = (tid & 15) * 4;
        #pragma unroll
        for (int i = 0; i < 4; i++) {
            int kr = rl + i * 16;
            float4 v4 = *(const float4*)&in[(size_t)(k0 + kr) * Cn + n0 + cl];
            float v[4] = {v4.x, v4.y, v4.z, v4.w};
            #pragma unroll
            for (int j = 0; j < 4; j++) {
                unsigned short hb = f2b(v[j]);
                th[cl + j][kr] = (short)hb;
                tl[cl + j][kr] = (short)f2b(v[j] - b2f(hb));
            }
        }
    }
    __syncthreads();
    {
        int ro = tid >> 2, co = (tid & 3) * 16;
        *(s16x8*)&oh[(size_t)(n0 + ro) * R + k0 + co]     = *(s16x8*)&th[ro][co];
        *(s16x8*)&oh[(size_t)(n0 + ro) * R + k0 + co + 8] = *(s16x8*)&th[ro][co + 8];
        *(s16x8*)&ol[(size_t)(n0 + ro) * R + k0 + co]     = *(s16x8*)&tl[ro][co];
        *(s16x8*)&ol[(size_t)(n0 + ro) * R + k0 + co + 8] = *(s16x8*)&tl[ro][co + 8];
    }
}

// ---------------------------------------------------------------------------
// fp32 [R,Cn] -> bf16 [Cn,R] transpose (single, for W_proj).
// ---------------------------------------------------------------------------
__global__ __launch_bounds__(256) void cvtT_bf16(
    const float* __restrict__ in, short* __restrict__ out, int R, int Cn)
{
    __shared__ short t[64][80];
    const int tid = threadIdx.x;
    const int k0 = blockIdx.y * 64;
    const int n0 = blockIdx.x * 64;
    {
        int rl = tid >> 4, cl = (tid & 15) * 4;
        #pragma unroll
        for (int i = 0; i < 4; i++) {
            int kr = rl + i * 16;
            float4 v = *(const float4*)&in[(size_t)(k0 + kr) * Cn + n0 + cl];
            t[cl + 0][kr] = (short)f2b(v.x);
            t[cl + 1][kr] = (short)f2b(v.y);
            t[cl + 2][kr] = (short)f2b(v.z);
            t[cl + 3][kr] = (short)f2b(v.w);
        }
    }
    __syncthreads();
    {
        int ro = tid >> 2, co = (tid & 3) * 16;
        *(s16x8*)&out[(size_t)(n0 + ro) * R + k0 + co]     = *(s16x8*)&t[ro][co];
        *(s16x8*)&out[(size_t)(n0 + ro) * R + k0 + co + 8] = *(s16x8*)&t[ro][co + 8];
    }
}

// ---------------------------------------------------------------------------
// qkv_qk: Q,K columns (N=2048), bf16x3, hi/lo scatter. Q pre-scaled by
// 8*log2(e). 2-phase double-buffered staging, one barrier per K-step.
// ---------------------------------------------------------------------------
#define QK_STAGE(buf, kk) do {                                          \
    _Pragma("unroll")                                                   \
    for (int j = 0; j < 2; j++) {                                       \
        int s = wave * 2 + j;                                           \
        int row = s * 16 + gr;                                          \
        size_t ga = (size_t)(m0 + row) * C_ + (kk) + gc;                \
        size_t gb = (size_t)(n0 + row) * C_ + (kk) + gc;                \
        gload_lds16(&Ah[ga],  &Ash[buf][s * 512]);                      \
        gload_lds16(&Al[ga],  &Asl[buf][s * 512]);                      \
        gload_lds16(&BTh[gb], &Bsh[buf][s * 512]);                      \
        gload_lds16(&BTl[gb], &Bsl[buf][s * 512]);                      \
    }                                                                   \
} while (0)

__global__ __launch_bounds__(256) void qkv_qk(
    const short* __restrict__ Ah, const short* __restrict__ Al,
    const short* __restrict__ BTh, const short* __restrict__ BTl,
    const float* __restrict__ bias,
    short* __restrict__ Qh, short* __restrict__ Ql,
    short* __restrict__ Kh, short* __restrict__ Kl)
{
    __shared__ short Ash[2][128 * 32], Asl[2][128 * 32];
    __shared__ short Bsh[2][128 * 32], Bsl[2][128 * 32];   // 64 KB total

    const int tid  = threadIdx.x;
    const int wave = tid >> 6, lane = tid & 63;
    const int wm = wave >> 1, wn = wave & 1;
    const int lm = lane & 15, lq = lane >> 4;
    // XCD-aware bijective swizzle: 512 blocks, 64 consecutive wg per XCD
    const int fid = blockIdx.y * 16 + blockIdx.x;
    const int wg  = (fid & 7) * 64 + (fid >> 3);
    const int n0  = (wg & 15) * 128;
    const int m0  = (wg >> 4) * 128;
    const int gr = (lane >> 2);
    const int gc = (lane & 3) * 8;

    f32x4 acc[4][4] = {};

    QK_STAGE(0, 0);
    __syncthreads();

    for (int it = 0; it < 32; ++it) {
        const int cur = it & 1;
        if (it < 31) QK_STAGE(cur ^ 1, (it + 1) * 32);   // fly under MFMA

        s16x8 ah[4], al[4], bh[4], bl[4];
        #pragma unroll
        for (int mi = 0; mi < 4; mi++) {
            int r = wm * 64 + mi * 16 + lm;
            ah[mi] = *(const s16x8*)&Ash[cur][r * 32 + lq * 8];
            al[mi] = *(const s16x8*)&Asl[cur][r * 32 + lq * 8];
        }
        #pragma unroll
        for (int nj = 0; nj < 4; nj++) {
            int r = wn * 64 + nj * 16 + lm;
            bh[nj] = *(const s16x8*)&Bsh[cur][r * 32 + lq * 8];
            bl[nj] = *(const s16x8*)&Bsl[cur][r * 32 + lq * 8];
        }
        #pragma unroll
        for (int mi = 0; mi < 4; mi++)
            #pragma unroll
            for (int nj = 0; nj < 4; nj++) {
                acc[mi][nj] = MFMA16(ah[mi], bh[nj], acc[mi][nj]);
                acc[mi][nj] = MFMA16(ah[mi], bl[nj], acc[mi][nj]);
                acc[mi][nj] = MFMA16(al[mi], bh[nj], acc[mi][nj]);
            }
        __syncthreads();   // drains next-tile vmcnt + WAR protect
    }

    #pragma unroll
    for (int nj = 0; nj < 4; nj++) {
        int n = n0 + wn * 64 + nj * 16 + lm;
        float bv = bias[n];
        int isK = n >> 10;
        int c = n & (C_ - 1);
        int h = c >> 6, d = c & (D_ - 1);
        short* dh = isK ? Kh : Qh;
        short* dl = isK ? Kl : Ql;
        // Q carries sqrt(D)=8 and log2(e): softmax runs in exp2 domain
        float scale = isK ? 1.0f : 11.541560327111708f;   // 8*log2(e)
        #pragma unroll
        for (int mi = 0; mi < 4; mi++) {
            #pragma unroll
            for (int r = 0; r < 4; r++) {
                int m  = m0 + wm * 64 + mi * 16 + lq * 4 + r;
                int bb = m >> 11, t = m & (T_ - 1);
                float v = (acc[mi][nj][r] + bv) * scale;
                size_t idx = (((size_t)bb * H_ + h) * T_ + t) * D_ + d;
                unsigned short hb = f2b(v);
                dh[idx] = (short)hb;
                dl[idx] = (short)f2b(v - b2f(hb));
            }
        }
    }
}

// ---------------------------------------------------------------------------
// qkv_v: V columns (N=1024), single bf16, scatter TRANSPOSED -> VT [B,H,D,T].
// 2-phase double-buffered.
// ---------------------------------------------------------------------------
#define V_STAGE(buf, kk) do {                                           \
    _Pragma("unroll")                                                   \
    for (int j = 0; j < 2; j++) {                                       \
        int s = wave * 2 + j;                                           \
        int row = s * 16 + gr;                                          \
        gload_lds16(&Ah[(size_t)(m0 + row) * C_ + (kk) + gc],           \
                    &Ash[buf][s * 512]);                                \
        gload_lds16(&BTh[(size_t)(n0 + row) * C_ + (kk) + gc],          \
                    &Bsh[buf][s * 512]);                                \
    }                                                                   \
} while (0)

__global__ __launch_bounds__(256) void qkv_v(
    const short* __restrict__ Ah, const short* __restrict__ BTh,
    const float* __restrict__ bias, short* __restrict__ VT)
{
    __shared__ short Ash[2][128 * 32];
    __shared__ short Bsh[2][128 * 32];   // 32 KB

    const int tid  = threadIdx.x;
    const int wave = tid >> 6, lane = tid & 63;
    const int wm = wave >> 1, wn = wave & 1;
    const int lm = lane & 15, lq = lane >> 4;
    // XCD swizzle: 256 blocks, 32 consecutive wg per XCD
    const int fid = blockIdx.y * 8 + blockIdx.x;
    const int wg  = (fid & 7) * 32 + (fid >> 3);
    const int n0  = (wg & 7) * 128;
    const int m0  = (wg >> 3) * 128;
    const int gr = (lane >> 2);
    const int gc = (lane & 3) * 8;

    f32x4 acc[4][4] = {};

    V_STAGE(0, 0);
    __syncthreads();

    for (int it = 0; it < 32; ++it) {
        const int cur = it & 1;
        if (it < 31) V_STAGE(cur ^ 1, (it + 1) * 32);

        s16x8 af[4], bfr[4];
        #pragma unroll
        for (int mi = 0; mi < 4; mi++)
            af[mi] = *(const s16x8*)&Ash[cur][(wm * 64 + mi * 16 + lm) * 32 + lq * 8];
        #pragma unroll
        for (int nj = 0; nj < 4; nj++)
            bfr[nj] = *(const s16x8*)&Bsh[cur][(wn * 64 + nj * 16 + lm) * 32 + lq * 8];
        #pragma unroll
        for (int mi = 0; mi < 4; mi++)
            #pragma unroll
            for (int nj = 0; nj < 4; nj++)
                acc[mi][nj] = MFMA16(af[mi], bfr[nj], acc[mi][nj]);
        __syncthreads();
    }

    #pragma unroll
    for (int nj = 0; nj < 4; nj++) {
        int n = n0 + wn * 64 + nj * 16 + lm;    // [0, 1024) V channel
        float bv = bias[n];
        int h = n >> 6, d = n & (D_ - 1);
        #pragma unroll
        for (int mi = 0; mi < 4; mi++) {
            #pragma unroll
            for (int r = 0; r < 4; r++) {
                int m  = m0 + wm * 64 + mi * 16 + lq * 4 + r;
                int bb = m >> 11, t = m & (T_ - 1);
                VT[(((size_t)bb * H_ + h) * D_ + d) * T_ + t] =
                    (short)f2b(acc[mi][nj][r] + bv);
            }
        }
    }
}

// ---------------------------------------------------------------------------
// proj: out fp32 [M,C] = Yb(bf16) @ WpT(bf16) + bias. 2-phase dbuf.
// ---------------------------------------------------------------------------
__global__ __launch_bounds__(256) void proj_mfma(
    const short* __restrict__ Ah, const short* __restrict__ BTh,
    const float* __restrict__ bias, float* __restrict__ out)
{
    __shared__ short Ash[2][128 * 32];
    __shared__ short Bsh[2][128 * 32];   // 32 KB

    const int tid  = threadIdx.x;
    const int wave = tid >> 6, lane = tid & 63;
    const int wm = wave >> 1, wn = wave & 1;
    const int lm = lane & 15, lq = lane >> 4;
    const int fid = blockIdx.y * 8 + blockIdx.x;
    const int wg  = (fid & 7) * 32 + (fid >> 3);
    const int n0  = (wg & 7) * 128;
    const int m0  = (wg >> 3) * 128;
    const int gr = (lane >> 2);
    const int gc = (lane & 3) * 8;

    f32x4 acc[4][4] = {};

    V_STAGE(0, 0);
    __syncthreads();

    for (int it = 0; it < 32; ++it) {
        const int cur = it & 1;
        if (it < 31) V_STAGE(cur ^ 1, (it + 1) * 32);

        s16x8 af[4], bfr[4];
        #pragma unroll
        for (int mi = 0; mi < 4; mi++)
            af[mi] = *(const s16x8*)&Ash[cur][(wm * 64 + mi * 16 + lm) * 32 + lq * 8];
        #pragma unroll
        for (int nj = 0; nj < 4; nj++)
            bfr[nj] = *(const s16x8*)&Bsh[cur][(wn * 64 + nj * 16 + lm) * 32 + lq * 8];
        #pragma unroll
        for (int mi = 0; mi < 4; mi++)
            #pragma unroll
            for (int nj = 0; nj < 4; nj++)
                acc[mi][nj] = MFMA16(af[mi], bfr[nj], acc[mi][nj]);
        __syncthreads();
    }

    #pragma unroll
    for (int nj = 0; nj < 4; nj++) {
        int n = n0 + wn * 64 + nj * 16 + lm;
        float bv = bias[n];
        #pragma unroll
        for (int mi = 0; mi < 4; mi++) {
            #pragma unroll
            for (int r = 0; r < 4; r++) {
                int m = m0 + wm * 64 + mi * 16 + lq * 4 + r;
                out[(size_t)m * C_ + n] = acc[mi][nj][r] + bv;
            }
        }
    }
}

// ---------------------------------------------------------------------------
// online softmax (exp2 domain) with defer-max (THR=8). S in/out: S^T frag,
// per-thread 16 values for q-row lm. On exit S holds P = exp2(S - m).
// ---------------------------------------------------------------------------
__device__ __forceinline__ void online_sm(
    f32x4 S[4], float& mrow, float& lrow, f32x4 O[4], int quad)
{
    float v[16];
    #pragma unroll
    for (int t = 0; t < 4; t++)
        #pragma unroll
        for (int r = 0; r < 4; r++) v[t * 4 + r] = S[t][r];
    #pragma unroll
    for (int s = 8; s; s >>= 1)
        #pragma unroll
        for (int i = 0; i < s; i++) v[i] = fmaxf(v[i], v[i + s]);
    float rm = v[0];
    rm = fmaxf(rm, __shfl_xor(rm, 16, 64));
    rm = fmaxf(rm, __shfl_xor(rm, 32, 64));
    // defer-max: only rescale when some row grew by > 8 (=2^8 headroom)
    if (!__all(rm - mrow <= 8.f)) {
        float mnew  = fmaxf(mrow, rm);
        float alpha = fexp2(mrow - mnew);
        mrow = mnew;
        lrow *= alpha;
        float al[4];
        #pragma unroll
        for (int r = 0; r < 4; r++) al[r] = __shfl(alpha, quad * 4 + r, 64);
        #pragma unroll
        for (int t = 0; t < 4; t++)
            #pragma unroll
            for (int r = 0; r < 4; r++) O[t][r] *= al[r];
    }
    float sv[16];
    #pragma unroll
    for (int t = 0; t < 4; t++)
        #pragma unroll
        for (int r = 0; r < 4; r++) {
            float p = fexp2(S[t][r] - mrow);
            S[t][r] = p;
            sv[t * 4 + r] = p;
        }
    #pragma unroll
    for (int s = 8; s; s >>= 1)
        #pragma unroll
        for (int i = 0; i < s; i++) sv[i] += sv[i + s];
    float rs = sv[0];
    rs += __shfl_xor(rs, 16, 64);
    rs += __shfl_xor(rs, 32, 64);
    lrow += rs;
}

// ---------------------------------------------------------------------------
// MFMA flash attention, S^T layout, PAIRED q-tiles per block. Grid 512.
// Block handles qtA=j (j in 0..15) and qtB=31-j of one (b,h): exactly 33
// compute-units each. K/V staged once per kt, shared by both tiles; for
// kt<=j one LDS k-frag read feeds 6 MFMAs (dual chains = intra-wave ILP).
// Slot map pairs j with 15-j -> per-CU iteration count 49 (constant).
// LDS 40KB, XOR-swizzled [64][64] (conflict-free), 2 blocks/CU.
// Q pre-scaled by 8*log2e; softmax exp2-domain with defer-max.
// ---------------------------------------------------------------------------
__global__ __launch_bounds__(256, 2) void attn_mfma(
    const short* __restrict__ Qh, const short* __restrict__ Ql,
    const short* __restrict__ Kh, const short* __restrict__ Kl,
    const short* __restrict__ VT, short* __restrict__ Yb)
{
    __shared__ short Ksh[64][64], Ksl[64][64];   // [key][d], XOR-swizzled
    __shared__ short Vt [64][64];                // [d][key], XOR-swizzled
    __shared__ short Ps [4][2][16][64];          // per-wave P slabs (B=0,A=1)

    const int tid  = threadIdx.x;
    const int wave = tid >> 6, lane = tid & 63;
    const int lm   = lane & 15, quad = lane >> 4;
    const int swz  = (lm & 7) << 3;              // read-side XOR (shorts)

    const int bid = blockIdx.x;                  // 512 blocks
    const int xcd = bid & 7;
    const int r_  = bid >> 3;                    // 0..63 per XCD
    const int bhl = r_ & 3;
    const int u   = r_ >> 2;                     // 0..15
    const int g_  = u >> 3, j_ = u & 7;
    const int j   = g_ ? (15 - j_) : j_;         // CU slot pairs j with 15-j
    const int bh  = xcd * 4 + bhl;
    const int b   = bh >> 4, h = bh & (H_ - 1);
    const int qtA = j, qtB = 31 - j;
    const int q0A = qtA * 64, q0B = qtB * 64;
    const size_t base  = (size_t)bh * T_ * D_;   // Q,K: [b,h,t,d]
    const size_t vbase = (size_t)bh * D_ * T_;   // VT:  [b,h,d,t]

    const int src = tid >> 3;                    // staging row 0..31 (+32)
    const int sch = (tid & 7) * 8;               // linear global col (shorts)
    const int wsw = sch ^ ((src & 7) << 3);      // swizzled LDS write col

    // ---- Q frags direct from global (L2-hit, once per block) ----
    s16x8 bqhA[2], bqlA[2], bqhB[2], bqlB[2];
    #pragma unroll
    for (int kc = 0; kc < 2; kc++) {
        size_t ga = base + (size_t)(q0A + wave * 16 + lm) * D_ + kc * 32 + quad * 8;
        size_t gb = base + (size_t)(q0B + wave * 16 + lm) * D_ + kc * 32 + quad * 8;
        bqhA[kc] = *(const s16x8*)&Qh[ga];
        bqlA[kc] = *(const s16x8*)&Ql[ga];
        bqhB[kc] = *(const s16x8*)&Qh[gb];
        bqlB[kc] = *(const s16x8*)&Ql[gb];
    }

    // ---- prefetch k-tile 0 into registers ----
    s16x8 pkh[2], pkl[2], pvt[2];
    #pragma unroll
    for (int i = 0; i < 2; i++) {
        int row = i * 32 + src;
        size_t gk = base + (size_t)row * D_ + sch;
        pkh[i] = *(const s16x8*)&Kh[gk];
        pkl[i] = *(const s16x8*)&Kl[gk];
        pvt[i] = *(const s16x8*)&VT[vbase + (size_t)row * T_ + sch];
    }

    float mA = -INFINITY, lA = 0.f;
    float mB = -INFINITY, lB = 0.f;
    f32x4 OA[4] = {}, OB[4] = {};

    for (int kt = 0; kt <= qtB; kt++) {
        __syncthreads();                          // prev tile's readers done
        #pragma unroll
        for (int i = 0; i < 2; i++) {             // VGPR -> LDS (swizzled)
            int row = i * 32 + src;
            *(s16x8*)&Ksh[row][wsw] = pkh[i];
            *(s16x8*)&Ksl[row][wsw] = pkl[i];
            *(s16x8*)&Vt [row][wsw] = pvt[i];
        }
        if (kt < qtB) {                           // issue next tile's loads
            #pragma unroll
            for (int i = 0; i < 2; i++) {
                int row = i * 32 + src;
                size_t gk = base + (size_t)((kt + 1) * 64 + row) * D_ + sch;
                pkh[i] = *(const s16x8*)&Kh[gk];
                pkl[i] = *(const s16x8*)&Kl[gk];
                pvt[i] = *(const s16x8*)&VT[vbase + (size_t)row * T_ + (kt + 1) * 64 + sch];
            }
        }
        __syncthreads();

        const bool doA = (kt <= qtA);
        const int  qg  = wave * 16 + lm;

        f32x4 SB[4] = {}, SA[4] = {};
        if (doA) {
            // dual: one k-frag read feeds 6 MFMAs (two independent chains)
            #pragma unroll
            for (int t = 0; t < 4; t++)
                #pragma unroll
                for (int kc = 0; kc < 2; kc++) {
                    s16x8 kh8 = *(const s16x8*)&Ksh[t * 16 + lm][(kc * 32 + quad * 8) ^ swz];
                    s16x8 kl8 = *(const s16x8*)&Ksl[t * 16 + lm][(kc * 32 + quad * 8) ^ swz];
                    SB[t] = MFMA16(kh8, bqhB[kc], SB[t]);
                    SB[t] = MFMA16(kl8, bqhB[kc], SB[t]);
                    SB[t] = MFMA16(kh8, bqlB[kc], SB[t]);
                    SA[t] = MFMA16(kh8, bqhA[kc], SA[t]);
                    SA[t] = MFMA16(kl8, bqhA[kc], SA[t]);
                    SA[t] = MFMA16(kh8, bqlA[kc], SA[t]);
                }
        } else {
            #pragma unroll
            for (int t = 0; t < 4; t++)
                #pragma unroll
                for (int kc = 0; kc < 2; kc++) {
                    s16x8 kh8 = *(const s16x8*)&Ksh[t * 16 + lm][(kc * 32 + quad * 8) ^ swz];
                    s16x8 kl8 = *(const s16x8*)&Ksl[t * 16 + lm][(kc * 32 + quad * 8) ^ swz];
                    SB[t] = MFMA16(kh8, bqhB[kc], SB[t]);
                    SB[t] = MFMA16(kl8, bqhB[kc], SB[t]);
                    SB[t] = MFMA16(kh8, bqlB[kc], SB[t]);
                }
        }

        // causal masks (scale pre-folded into Q)
        if (kt == qtB) {
            #pragma unroll
            for (int t = 0; t < 4; t++)
                #pragma unroll
                for (int r = 0; r < 4; r++)
                    if ((t * 16 + quad * 4 + r) > qg) SB[t][r] = -INFINITY;
        }
        if (kt == qtA) {
            #pragma unroll
            for (int t = 0; t < 4; t++)
                #pragma unroll
                for (int r = 0; r < 4; r++)
                    if ((t * 16 + quad * 4 + r) > qg) SA[t][r] = -INFINITY;
        }

        // ---- softmax (dual chains are independent) ----
        online_sm(SB, mB, lB, OB, quad);
        if (doA) online_sm(SA, mA, lA, OA, quad);

        // ---- P^T -> Ps (truncating bf16; P in [0, 256]) ----
        #pragma unroll
        for (int t = 0; t < 4; t++) {
            s16x4 p;
            #pragma unroll
            for (int r = 0; r < 4; r++)
                p[r] = (short)(__float_as_uint(SB[t][r]) >> 16);
            *(s16x4*)&Ps[wave][0][lm][(t * 16 + quad * 4) ^ swz] = p;
        }
        if (doA) {
            #pragma unroll
            for (int t = 0; t < 4; t++) {
                s16x4 p;
                #pragma unroll
                for (int r = 0; r < 4; r++)
                    p[r] = (short)(__float_as_uint(SA[t][r]) >> 16);
                *(s16x4*)&Ps[wave][1][lm][(t * 16 + quad * 4) ^ swz] = p;
            }
        }
        // wave-private slabs: no barrier (lgkmcnt ordering within wave)

        // ---- O += P V: shared Vt frag feeds both tiles ----
        s16x8 apB[2], apA[2];
        #pragma unroll
        for (int kc = 0; kc < 2; kc++)
            apB[kc] = *(const s16x8*)&Ps[wave][0][lm][(kc * 32 + quad * 8) ^ swz];
        if (doA) {
            #pragma unroll
            for (int kc = 0; kc < 2; kc++)
                apA[kc] = *(const s16x8*)&Ps[wave][1][lm][(kc * 32 + quad * 8) ^ swz];
            #pragma unroll
            for (int t = 0; t < 4; t++)
                #pragma unroll
                for (int kc = 0; kc < 2; kc++) {
                    s16x8 bv = *(const s16x8*)&Vt[t * 16 + lm][(kc * 32 + quad * 8) ^ swz];
                    OB[t] = MFMA16(apB[kc], bv, OB[t]);
                    OA[t] = MFMA16(apA[kc], bv, OA[t]);
                }
        } else {
            #pragma unroll
            for (int t = 0; t < 4; t++)
                #pragma unroll
                for (int kc = 0; kc < 2; kc++) {
                    s16x8 bv = *(const s16x8*)&Vt[t * 16 + lm][(kc * 32 + quad * 8) ^ swz];
                    OB[t] = MFMA16(apB[kc], bv, OB[t]);
                }
        }
    }

    // ---- epilogue: row q = wave*16+quad*4+r, col d = t*16+lm ----
    float liA[4], liB[4];
    #pragma unroll
    for (int r = 0; r < 4; r++) {
        liA[r] = 1.0f / __shfl(lA, quad * 4 + r, 64);
        liB[r] = 1.0f / __shfl(lB, quad * 4 + r, 64);
    }
    #pragma unroll
    for (int t = 0; t < 4; t++)
        #pragma unroll
        for (int r = 0; r < 4; r++) {
            int d  = t * 16 + lm;
            int qa = q0A + wave * 16 + quad * 4 + r;
            int qb = q0B + wave * 16 + quad * 4 + r;
            Yb[((size_t)b * T_ + qa) * C_ + h * D_ + d] =
                (short)f2b(OA[t][r] * liA[r]);
            Yb[((size_t)b * T_ + qb) * C_ + h * D_ + d] =
                (short)f2b(OB[t][r] * liB[r]);
        }
}

// ---------------------------------------------------------------------------
extern "C" void kernel_launch(void* const* d_in, const int* in_sizes, int n_in,
                              void* d_out, int out_size, void* d_ws, size_t ws_size,
                              hipStream_t stream)
{
    const float* x      = (const float*)d_in[0];
    const float* W_attn = (const float*)d_in[1];
    const float* b_attn = (const float*)d_in[2];
    const float* W_proj = (const float*)d_in[3];
    const float* b_proj = (const float*)d_in[4];
    float* out = (float*)d_out;

    char* ws = (char*)d_ws;
    const size_t MB = 1024 * 1024;
    short* Qh   = (short*)(ws);            // 8 MB  [ 0, 8)
    short* Ql   = (short*)(ws +  8 * MB);  // 8 MB  [ 8,16)
    short* Kh   = (short*)(ws + 16 * MB);  // 8 MB  [16,24)
    short* Kl   = (short*)(ws + 24 * MB);  // 8 MB  [24,32)
    short* xh   = (short*)(ws + 32 * MB);  // 8 MB  [32,40)  dead after qkv_v
    short* xl   = (short*)(ws + 40 * MB);  // 8 MB  [40,48)  dead after qkv_qk
    short* WaTh = (short*)(ws + 48 * MB);  // 6 MB  [48,54)
    short* WaTl = (short*)(ws + 54 * MB);  // 6 MB  [54,60)
    short* WpT  = (short*)(ws + 60 * MB);  // 2 MB  [60,62)
    short* VT   = (short*)(ws + 40 * MB);  // 8 MB  aliases xl (born at qkv_v)
    short* Yb   = (short*)(ws + 32 * MB);  // 8 MB  aliases xh (born at attn)

    cvt_split <<<dim3(M_ * C_ / 2048), 256, 0, stream>>>(x, xh, xl, M_ * C_);
    cvtT_split<<<dim3(N3_ / 64, C_ / 64), 256, 0, stream>>>(W_attn, WaTh, WaTl, C_, N3_);
    cvtT_bf16 <<<dim3(C_ / 64, C_ / 64), 256, 0, stream>>>(W_proj, WpT, C_, C_);

    qkv_qk <<<dim3(16, 32), 256, 0, stream>>>(xh, xl, WaTh, WaTl, b_attn,
                                              Qh, Ql, Kh, Kl);
    qkv_v  <<<dim3(8, 32), 256, 0, stream>>>(xh, WaTh + (size_t)2048 * C_,
                                             b_attn + 2048, VT);
    attn_mfma<<<dim3(512), 256, 0, stream>>>(Qh, Ql, Kh, Kl, VT, Yb);
    proj_mfma<<<dim3(8, 32), 256, 0, stream>>>(Yb, WpT, b_proj, out);
}

// Round 3
// 246.857 us; speedup vs baseline: 1.0862x; 1.0862x over previous
//
#include <hip/hip_runtime.h>
#include <hip/hip_bf16.h>

// Problem: CausalSelfAttention  B=2, T=2048, C=1024, H=16, D=64
// Round 15: GEMM TLP attack. R14's dbuf+swizzle REGRESSED (68->75us qkv_qk):
// the "overlap" was the same loop rotation the barrier drain already gave,
// and swizzle lockstep hurt. Reverted both. Real finding: qkv_v/proj ran at
// 1 block/CU (grid 256!) and qkv_qk at 2 -- staging-latency loops with no
// TLP to hide under (qkv_v/proj ~245 TF eff). Fix: M-split 128x128 ->
// 64x128 tiles. qkv_qk grid 1024 = 4 blocks/CU (16 waves), qkv_v/proj
// grid 512 = 2 blocks/CU. Single-buffer 2-barrier structure (proven R13),
// LDS 24/12 KB. attn (paired q-tiles, XOR swizzle, defer-max) unchanged.
// ws (62 MB): Qh 8|Ql 8|Kh 8|Kl 8|xh 8(->Yb)|xl 8(->VT)|WaTh 6|WaTl 6|WpT 2

#define B_  2
#define T_  2048
#define C_  1024
#define H_  16
#define D_  64
#define M_  (B_ * T_)      // 4096
#define N3_ (3 * C_)       // 3072

typedef __attribute__((ext_vector_type(8))) short s16x8;
typedef __attribute__((ext_vector_type(4))) short s16x4;
typedef __attribute__((ext_vector_type(4))) float f32x4;

typedef const __attribute__((address_space(1))) unsigned int gu32_t;
typedef __attribute__((address_space(3))) unsigned int lu32_t;

#define MFMA16(a, b, c) __builtin_amdgcn_mfma_f32_16x16x32_bf16(a, b, c, 0, 0, 0)

__device__ __forceinline__ void gload_lds16(const short* g, short* l) {
    __builtin_amdgcn_global_load_lds((gu32_t*)g, (lu32_t*)l, 16, 0, 0);
}

__device__ __forceinline__ float b2f(unsigned short u) {
    return __uint_as_float(((unsigned)u) << 16);
}
__device__ __forceinline__ unsigned short f2b(float f) {   // RNE bf16 round
    unsigned u = __float_as_uint(f);
    return (unsigned short)((u + 0x7FFFu + ((u >> 16) & 1u)) >> 16);
}
__device__ __forceinline__ float fexp2(float x) {
#if __has_builtin(__builtin_amdgcn_exp2f)
    return __builtin_amdgcn_exp2f(x);
#else
    return exp2f(x);
#endif
}

// ---------------------------------------------------------------------------
// fp32 -> (hi, lo) bf16 split. n multiple of 2048.
// ---------------------------------------------------------------------------
__global__ __launch_bounds__(256) void cvt_split(
    const float* __restrict__ in, short* __restrict__ oh, short* __restrict__ ol, int n)
{
    int i = (blockIdx.x * 256 + threadIdx.x) * 8;
    if (i >= n) return;
    float4 a = *(const float4*)&in[i];
    float4 b = *(const float4*)&in[i + 4];
    float v[8] = {a.x, a.y, a.z, a.w, b.x, b.y, b.z, b.w};
    s16x8 h, l;
    #pragma unroll
    for (int j = 0; j < 8; j++) {
        unsigned short hb = f2b(v[j]);
        h[j] = (short)hb;
        l[j] = (short)f2b(v[j] - b2f(hb));
    }
    *(s16x8*)&oh[i] = h;
    *(s16x8*)&ol[i] = l;
}

// ---------------------------------------------------------------------------
// fp32 [R,Cn] -> (hi,lo) bf16 [Cn,R] transpose+split. grid (Cn/64, R/64).
// ---------------------------------------------------------------------------
__global__ __launch_bounds__(256) void cvtT_split(
    const float* __restrict__ in, short* __restrict__ oh, short* __restrict__ ol,
    int R, int Cn)
{
    __shared__ short th[64][80];
    __shared__ short tl[64][80];
    const int tid = threadIdx.x;
    const int k0 = blockIdx.y * 64;
    const int n0 = blockIdx.x * 64;
    {
        int rl = tid >> 4, cl = (tid & 15) * 4;
        #pragma unroll
        for (int i = 0; i < 4; i++) {
            int kr = rl + i * 16;
            float4 v4 = *(const float4*)&in[(size_t)(k0 + kr) * Cn + n0 + cl];
            float v[4] = {v4.x, v4.y, v4.z, v4.w};
            #pragma unroll
            for (int j = 0; j < 4; j++) {
                unsigned short hb = f2b(v[j]);
                th[cl + j][kr] = (short)hb;
                tl[cl + j][kr] = (short)f2b(v[j] - b2f(hb));
            }
        }
    }
    __syncthreads();
    {
        int ro = tid >> 2, co = (tid & 3) * 16;
        *(s16x8*)&oh[(size_t)(n0 + ro) * R + k0 + co]     = *(s16x8*)&th[ro][co];
        *(s16x8*)&oh[(size_t)(n0 + ro) * R + k0 + co + 8] = *(s16x8*)&th[ro][co + 8];
        *(s16x8*)&ol[(size_t)(n0 + ro) * R + k0 + co]     = *(s16x8*)&tl[ro][co];
        *(s16x8*)&ol[(size_t)(n0 + ro) * R + k0 + co + 8] = *(s16x8*)&tl[ro][co + 8];
    }
}

// ---------------------------------------------------------------------------
// fp32 [R,Cn] -> bf16 [Cn,R] transpose (single, for W_proj).
// ---------------------------------------------------------------------------
__global__ __launch_bounds__(256) void cvtT_bf16(
    const float* __restrict__ in, short* __restrict__ out, int R, int Cn)
{
    __shared__ short t[64][80];
    const int tid = threadIdx.x;
    const int k0 = blockIdx.y * 64;
    const int n0 = blockIdx.x * 64;
    {
        int rl = tid >> 4, cl = (tid & 15) * 4;
        #pragma unroll
        for (int i = 0; i < 4; i++) {
            int kr = rl + i * 16;
            float4 v = *(const float4*)&in[(size_t)(k0 + kr) * Cn + n0 + cl];
            t[cl + 0][kr] = (short)f2b(v.x);
            t[cl + 1][kr] = (short)f2b(v.y);
            t[cl + 2][kr] = (short)f2b(v.z);
            t[cl + 3][kr] = (short)f2b(v.w);
        }
    }
    __syncthreads();
    {
        int ro = tid >> 2, co = (tid & 3) * 16;
        *(s16x8*)&out[(size_t)(n0 + ro) * R + k0 + co]     = *(s16x8*)&t[ro][co];
        *(s16x8*)&out[(size_t)(n0 + ro) * R + k0 + co + 8] = *(s16x8*)&t[ro][co + 8];
    }
}

// ---------------------------------------------------------------------------
// qkv_qk: Q,K columns (N=2048), bf16x3, hi/lo scatter. Q pre-scaled by
// 8*log2(e). 64x128 tile, grid (16,64)=1024 blocks = 4 blocks/CU.
// Single-buffer 2-barrier K-loop (R13 structure), LDS 24 KB.
// ---------------------------------------------------------------------------
__global__ __launch_bounds__(256, 4) void qkv_qk(
    const short* __restrict__ Ah, const short* __restrict__ Al,
    const short* __restrict__ BTh, const short* __restrict__ BTl,
    const float* __restrict__ bias,
    short* __restrict__ Qh, short* __restrict__ Ql,
    short* __restrict__ Kh, short* __restrict__ Kl)
{
    __shared__ short Ash[64 * 32], Asl[64 * 32];     // 4 KB each
    __shared__ short Bsh[128 * 32], Bsl[128 * 32];   // 8 KB each

    const int tid  = threadIdx.x;
    const int wave = tid >> 6, lane = tid & 63;
    const int wm = wave >> 1, wn = wave & 1;
    const int lm = lane & 15, lq = lane >> 4;
    const int m0 = blockIdx.y * 64, n0 = blockIdx.x * 128;
    const int gr = (lane >> 2);
    const int gc = (lane & 3) * 8;

    f32x4 acc[2][4] = {};

    for (int k0 = 0; k0 < C_; k0 += 32) {
        __syncthreads();
        {
            int rowA = wave * 16 + gr;                       // A: 4 segs
            size_t ga = (size_t)(m0 + rowA) * C_ + k0 + gc;
            gload_lds16(&Ah[ga], &Ash[wave * 512]);
            gload_lds16(&Al[ga], &Asl[wave * 512]);
            #pragma unroll
            for (int j = 0; j < 2; j++) {                    // B: 8 segs
                int s = wave * 2 + j;
                int rowB = s * 16 + gr;
                size_t gb = (size_t)(n0 + rowB) * C_ + k0 + gc;
                gload_lds16(&BTh[gb], &Bsh[s * 512]);
                gload_lds16(&BTl[gb], &Bsl[s * 512]);
            }
        }
        __syncthreads();

        s16x8 ah[2], al[2], bh[4], bl[4];
        #pragma unroll
        for (int mi = 0; mi < 2; mi++) {
            int r = wm * 32 + mi * 16 + lm;
            ah[mi] = *(const s16x8*)&Ash[r * 32 + lq * 8];
            al[mi] = *(const s16x8*)&Asl[r * 32 + lq * 8];
        }
        #pragma unroll
        for (int nj = 0; nj < 4; nj++) {
            int r = wn * 64 + nj * 16 + lm;
            bh[nj] = *(const s16x8*)&Bsh[r * 32 + lq * 8];
            bl[nj] = *(const s16x8*)&Bsl[r * 32 + lq * 8];
        }
        #pragma unroll
        for (int mi = 0; mi < 2; mi++)
            #pragma unroll
            for (int nj = 0; nj < 4; nj++) {
                acc[mi][nj] = MFMA16(ah[mi], bh[nj], acc[mi][nj]);
                acc[mi][nj] = MFMA16(ah[mi], bl[nj], acc[mi][nj]);
                acc[mi][nj] = MFMA16(al[mi], bh[nj], acc[mi][nj]);
            }
    }

    #pragma unroll
    for (int nj = 0; nj < 4; nj++) {
        int n = n0 + wn * 64 + nj * 16 + lm;
        float bv = bias[n];
        int isK = n >> 10;
        int c = n & (C_ - 1);
        int h = c >> 6, d = c & (D_ - 1);
        short* dh = isK ? Kh : Qh;
        short* dl = isK ? Kl : Ql;
        // Q carries sqrt(D)=8 and log2(e): softmax runs in exp2 domain
        float scale = isK ? 1.0f : 11.541560327111708f;   // 8*log2(e)
        #pragma unroll
        for (int mi = 0; mi < 2; mi++) {
            #pragma unroll
            for (int r = 0; r < 4; r++) {
                int m  = m0 + wm * 32 + mi * 16 + lq * 4 + r;
                int bb = m >> 11, t = m & (T_ - 1);
                float v = (acc[mi][nj][r] + bv) * scale;
                size_t idx = (((size_t)bb * H_ + h) * T_ + t) * D_ + d;
                unsigned short hb = f2b(v);
                dh[idx] = (short)hb;
                dl[idx] = (short)f2b(v - b2f(hb));
            }
        }
    }
}

// ---------------------------------------------------------------------------
// qkv_v: V columns (N=1024), single bf16, scatter TRANSPOSED -> VT [B,H,D,T].
// 64x128 tile, grid (8,64)=512 blocks = 2 blocks/CU. LDS 12 KB.
// ---------------------------------------------------------------------------
__global__ __launch_bounds__(256, 4) void qkv_v(
    const short* __restrict__ Ah, const short* __restrict__ BTh,
    const float* __restrict__ bias, short* __restrict__ VT)
{
    __shared__ short Ash[64 * 32];    // 4 KB
    __shared__ short Bsh[128 * 32];   // 8 KB

    const int tid  = threadIdx.x;
    const int wave = tid >> 6, lane = tid & 63;
    const int wm = wave >> 1, wn = wave & 1;
    const int lm = lane & 15, lq = lane >> 4;
    const int m0 = blockIdx.y * 64, n0 = blockIdx.x * 128;
    const int gr = (lane >> 2);
    const int gc = (lane & 3) * 8;

    f32x4 acc[2][4] = {};

    for (int k0 = 0; k0 < C_; k0 += 32) {
        __syncthreads();
        {
            int rowA = wave * 16 + gr;
            gload_lds16(&Ah[(size_t)(m0 + rowA) * C_ + k0 + gc], &Ash[wave * 512]);
            #pragma unroll
            for (int j = 0; j < 2; j++) {
                int s = wave * 2 + j;
                int rowB = s * 16 + gr;
                gload_lds16(&BTh[(size_t)(n0 + rowB) * C_ + k0 + gc], &Bsh[s * 512]);
            }
        }
        __syncthreads();

        s16x8 af[2], bfr[4];
        #pragma unroll
        for (int mi = 0; mi < 2; mi++)
            af[mi] = *(const s16x8*)&Ash[(wm * 32 + mi * 16 + lm) * 32 + lq * 8];
        #pragma unroll
        for (int nj = 0; nj < 4; nj++)
            bfr[nj] = *(const s16x8*)&Bsh[(wn * 64 + nj * 16 + lm) * 32 + lq * 8];
        #pragma unroll
        for (int mi = 0; mi < 2; mi++)
            #pragma unroll
            for (int nj = 0; nj < 4; nj++)
                acc[mi][nj] = MFMA16(af[mi], bfr[nj], acc[mi][nj]);
    }

    #pragma unroll
    for (int nj = 0; nj < 4; nj++) {
        int n = n0 + wn * 64 + nj * 16 + lm;    // [0, 1024) V channel
        float bv = bias[n];
        int h = n >> 6, d = n & (D_ - 1);
        #pragma unroll
        for (int mi = 0; mi < 2; mi++) {
            #pragma unroll
            for (int r = 0; r < 4; r++) {
                int m  = m0 + wm * 32 + mi * 16 + lq * 4 + r;
                int bb = m >> 11, t = m & (T_ - 1);
                VT[(((size_t)bb * H_ + h) * D_ + d) * T_ + t] =
                    (short)f2b(acc[mi][nj][r] + bv);
            }
        }
    }
}

// ---------------------------------------------------------------------------
// proj: out fp32 [M,C] = Yb(bf16) @ WpT(bf16) + bias. 64x128 tile, grid 512.
// ---------------------------------------------------------------------------
__global__ __launch_bounds__(256, 4) void proj_mfma(
    const short* __restrict__ Ah, const short* __restrict__ BTh,
    const float* __restrict__ bias, float* __restrict__ out)
{
    __shared__ short Ash[64 * 32];
    __shared__ short Bsh[128 * 32];

    const int tid  = threadIdx.x;
    const int wave = tid >> 6, lane = tid & 63;
    const int wm = wave >> 1, wn = wave & 1;
    const int lm = lane & 15, lq = lane >> 4;
    const int m0 = blockIdx.y * 64, n0 = blockIdx.x * 128;
    const int gr = (lane >> 2);
    const int gc = (lane & 3) * 8;

    f32x4 acc[2][4] = {};

    for (int k0 = 0; k0 < C_; k0 += 32) {
        __syncthreads();
        {
            int rowA = wave * 16 + gr;
            gload_lds16(&Ah[(size_t)(m0 + rowA) * C_ + k0 + gc], &Ash[wave * 512]);
            #pragma unroll
            for (int j = 0; j < 2; j++) {
                int s = wave * 2 + j;
                int rowB = s * 16 + gr;
                gload_lds16(&BTh[(size_t)(n0 + rowB) * C_ + k0 + gc], &Bsh[s * 512]);
            }
        }
        __syncthreads();

        s16x8 af[2], bfr[4];
        #pragma unroll
        for (int mi = 0; mi < 2; mi++)
            af[mi] = *(const s16x8*)&Ash[(wm * 32 + mi * 16 + lm) * 32 + lq * 8];
        #pragma unroll
        for (int nj = 0; nj < 4; nj++)
            bfr[nj] = *(const s16x8*)&Bsh[(wn * 64 + nj * 16 + lm) * 32 + lq * 8];
        #pragma unroll
        for (int mi = 0; mi < 2; mi++)
            #pragma unroll
            for (int nj = 0; nj < 4; nj++)
                acc[mi][nj] = MFMA16(af[mi], bfr[nj], acc[mi][nj]);
    }

    #pragma unroll
    for (int nj = 0; nj < 4; nj++) {
        int n = n0 + wn * 64 + nj * 16 + lm;
        float bv = bias[n];
        #pragma unroll
        for (int mi = 0; mi < 2; mi++) {
            #pragma unroll
            for (int r = 0; r < 4; r++) {
                int m = m0 + wm * 32 + mi * 16 + lq * 4 + r;
                out[(size_t)m * C_ + n] = acc[mi][nj][r] + bv;
            }
        }
    }
}

// ---------------------------------------------------------------------------
// online softmax (exp2 domain) with defer-max (THR=8). S in/out: S^T frag,
// per-thread 16 values for q-row lm. On exit S holds P = exp2(S - m).
// ---------------------------------------------------------------------------
__device__ __forceinline__ void online_sm(
    f32x4 S[4], float& mrow, float& lrow, f32x4 O[4], int quad)
{
    float v[16];
    #pragma unroll
    for (int t = 0; t < 4; t++)
        #pragma unroll
        for (int r = 0; r < 4; r++) v[t * 4 + r] = S[t][r];
    #pragma unroll
    for (int s = 8; s; s >>= 1)
        #pragma unroll
        for (int i = 0; i < s; i++) v[i] = fmaxf(v[i], v[i + s]);
    float rm = v[0];
    rm = fmaxf(rm, __shfl_xor(rm, 16, 64));
    rm = fmaxf(rm, __shfl_xor(rm, 32, 64));
    // defer-max: only rescale when some row grew by > 8 (=2^8 headroom)
    if (!__all(rm - mrow <= 8.f)) {
        float mnew  = fmaxf(mrow, rm);
        float alpha = fexp2(mrow - mnew);
        mrow = mnew;
        lrow *= alpha;
        float al[4];
        #pragma unroll
        for (int r = 0; r < 4; r++) al[r] = __shfl(alpha, quad * 4 + r, 64);
        #pragma unroll
        for (int t = 0; t < 4; t++)
            #pragma unroll
            for (int r = 0; r < 4; r++) O[t][r] *= al[r];
    }
    float sv[16];
    #pragma unroll
    for (int t = 0; t < 4; t++)
        #pragma unroll
        for (int r = 0; r < 4; r++) {
            float p = fexp2(S[t][r] - mrow);
            S[t][r] = p;
            sv[t * 4 + r] = p;
        }
    #pragma unroll
    for (int s = 8; s; s >>= 1)
        #pragma unroll
        for (int i = 0; i < s; i++) sv[i] += sv[i + s];
    float rs = sv[0];
    rs += __shfl_xor(rs, 16, 64);
    rs += __shfl_xor(rs, 32, 64);
    lrow += rs;
}

// ---------------------------------------------------------------------------
// MFMA flash attention, S^T layout, PAIRED q-tiles per block. Grid 512.
// Block handles qtA=j (j in 0..15) and qtB=31-j of one (b,h): exactly 33
// compute-units each. K/V staged once per kt, shared by both tiles; for
// kt<=j one LDS k-frag read feeds 6 MFMAs (dual chains = intra-wave ILP).
// Slot map pairs j with 15-j -> per-CU iteration count 49 (constant).
// LDS 40KB, XOR-swizzled [64][64] (conflict-free), 2 blocks/CU.
// Q pre-scaled by 8*log2e; softmax exp2-domain with defer-max.
// ---------------------------------------------------------------------------
__global__ __launch_bounds__(256, 2) void attn_mfma(
    const short* __restrict__ Qh, const short* __restrict__ Ql,
    const short* __restrict__ Kh, const short* __restrict__ Kl,
    const short* __restrict__ VT, short* __restrict__ Yb)
{
    __shared__ short Ksh[64][64], Ksl[64][64];   // [key][d], XOR-swizzled
    __shared__ short Vt [64][64];                // [d][key], XOR-swizzled
    __shared__ short Ps [4][2][16][64];          // per-wave P slabs (B=0,A=1)

    const int tid  = threadIdx.x;
    const int wave = tid >> 6, lane = tid & 63;
    const int lm   = lane & 15, quad = lane >> 4;
    const int swz  = (lm & 7) << 3;              // read-side XOR (shorts)

    const int bid = blockIdx.x;                  // 512 blocks
    const int xcd = bid & 7;
    const int r_  = bid >> 3;                    // 0..63 per XCD
    const int bhl = r_ & 3;
    const int u   = r_ >> 2;                     // 0..15
    const int g_  = u >> 3, j_ = u & 7;
    const int j   = g_ ? (15 - j_) : j_;         // CU slot pairs j with 15-j
    const int bh  = xcd * 4 + bhl;
    const int b   = bh >> 4, h = bh & (H_ - 1);
    const int qtA = j, qtB = 31 - j;
    const int q0A = qtA * 64, q0B = qtB * 64;
    const size_t base  = (size_t)bh * T_ * D_;   // Q,K: [b,h,t,d]
    const size_t vbase = (size_t)bh * D_ * T_;   // VT:  [b,h,d,t]

    const int src = tid >> 3;                    // staging row 0..31 (+32)
    const int sch = (tid & 7) * 8;               // linear global col (shorts)
    const int wsw = sch ^ ((src & 7) << 3);      // swizzled LDS write col

    // ---- Q frags direct from global (L2-hit, once per block) ----
    s16x8 bqhA[2], bqlA[2], bqhB[2], bqlB[2];
    #pragma unroll
    for (int kc = 0; kc < 2; kc++) {
        size_t ga = base + (size_t)(q0A + wave * 16 + lm) * D_ + kc * 32 + quad * 8;
        size_t gb = base + (size_t)(q0B + wave * 16 + lm) * D_ + kc * 32 + quad * 8;
        bqhA[kc] = *(const s16x8*)&Qh[ga];
        bqlA[kc] = *(const s16x8*)&Ql[ga];
        bqhB[kc] = *(const s16x8*)&Qh[gb];
        bqlB[kc] = *(const s16x8*)&Ql[gb];
    }

    // ---- prefetch k-tile 0 into registers ----
    s16x8 pkh[2], pkl[2], pvt[2];
    #pragma unroll
    for (int i = 0; i < 2; i++) {
        int row = i * 32 + src;
        size_t gk = base + (size_t)row * D_ + sch;
        pkh[i] = *(const s16x8*)&Kh[gk];
        pkl[i] = *(const s16x8*)&Kl[gk];
        pvt[i] = *(const s16x8*)&VT[vbase + (size_t)row * T_ + sch];
    }

    float mA = -INFINITY, lA = 0.f;
    float mB = -INFINITY, lB = 0.f;
    f32x4 OA[4] = {}, OB[4] = {};

    for (int kt = 0; kt <= qtB; kt++) {
        __syncthreads();                          // prev tile's readers done
        #pragma unroll
        for (int i = 0; i < 2; i++) {             // VGPR -> LDS (swizzled)
            int row = i * 32 + src;
            *(s16x8*)&Ksh[row][wsw] = pkh[i];
            *(s16x8*)&Ksl[row][wsw] = pkl[i];
            *(s16x8*)&Vt [row][wsw] = pvt[i];
        }
        if (kt < qtB) {                           // issue next tile's loads
            #pragma unroll
            for (int i = 0; i < 2; i++) {
                int row = i * 32 + src;
                size_t gk = base + (size_t)((kt + 1) * 64 + row) * D_ + sch;
                pkh[i] = *(const s16x8*)&Kh[gk];
                pkl[i] = *(const s16x8*)&Kl[gk];
                pvt[i] = *(const s16x8*)&VT[vbase + (size_t)row * T_ + (kt + 1) * 64 + sch];
            }
        }
        __syncthreads();

        const bool doA = (kt <= qtA);
        const int  qg  = wave * 16 + lm;

        f32x4 SB[4] = {}, SA[4] = {};
        if (doA) {
            // dual: one k-frag read feeds 6 MFMAs (two independent chains)
            #pragma unroll
            for (int t = 0; t < 4; t++)
                #pragma unroll
                for (int kc = 0; kc < 2; kc++) {
                    s16x8 kh8 = *(const s16x8*)&Ksh[t * 16 + lm][(kc * 32 + quad * 8) ^ swz];
                    s16x8 kl8 = *(const s16x8*)&Ksl[t * 16 + lm][(kc * 32 + quad * 8) ^ swz];
                    SB[t] = MFMA16(kh8, bqhB[kc], SB[t]);
                    SB[t] = MFMA16(kl8, bqhB[kc], SB[t]);
                    SB[t] = MFMA16(kh8, bqlB[kc], SB[t]);
                    SA[t] = MFMA16(kh8, bqhA[kc], SA[t]);
                    SA[t] = MFMA16(kl8, bqhA[kc], SA[t]);
                    SA[t] = MFMA16(kh8, bqlA[kc], SA[t]);
                }
        } else {
            #pragma unroll
            for (int t = 0; t < 4; t++)
                #pragma unroll
                for (int kc = 0; kc < 2; kc++) {
                    s16x8 kh8 = *(const s16x8*)&Ksh[t * 16 + lm][(kc * 32 + quad * 8) ^ swz];
                    s16x8 kl8 = *(const s16x8*)&Ksl[t * 16 + lm][(kc * 32 + quad * 8) ^ swz];
                    SB[t] = MFMA16(kh8, bqhB[kc], SB[t]);
                    SB[t] = MFMA16(kl8, bqhB[kc], SB[t]);
                    SB[t] = MFMA16(kh8, bqlB[kc], SB[t]);
                }
        }

        // causal masks (scale pre-folded into Q)
        if (kt == qtB) {
            #pragma unroll
            for (int t = 0; t < 4; t++)
                #pragma unroll
                for (int r = 0; r < 4; r++)
                    if ((t * 16 + quad * 4 + r) > qg) SB[t][r] = -INFINITY;
        }
        if (kt == qtA) {
            #pragma unroll
            for (int t = 0; t < 4; t++)
                #pragma unroll
                for (int r = 0; r < 4; r++)
                    if ((t * 16 + quad * 4 + r) > qg) SA[t][r] = -INFINITY;
        }

        // ---- softmax (dual chains are independent) ----
        online_sm(SB, mB, lB, OB, quad);
        if (doA) online_sm(SA, mA, lA, OA, quad);

        // ---- P^T -> Ps (truncating bf16; P in [0, 256]) ----
        #pragma unroll
        for (int t = 0; t < 4; t++) {
            s16x4 p;
            #pragma unroll
            for (int r = 0; r < 4; r++)
                p[r] = (short)(__float_as_uint(SB[t][r]) >> 16);
            *(s16x4*)&Ps[wave][0][lm][(t * 16 + quad * 4) ^ swz] = p;
        }
        if (doA) {
            #pragma unroll
            for (int t = 0; t < 4; t++) {
                s16x4 p;
                #pragma unroll
                for (int r = 0; r < 4; r++)
                    p[r] = (short)(__float_as_uint(SA[t][r]) >> 16);
                *(s16x4*)&Ps[wave][1][lm][(t * 16 + quad * 4) ^ swz] = p;
            }
        }
        // wave-private slabs: no barrier (lgkmcnt ordering within wave)

        // ---- O += P V: shared Vt frag feeds both tiles ----
        s16x8 apB[2], apA[2];
        #pragma unroll
        for (int kc = 0; kc < 2; kc++)
            apB[kc] = *(const s16x8*)&Ps[wave][0][lm][(kc * 32 + quad * 8) ^ swz];
        if (doA) {
            #pragma unroll
            for (int kc = 0; kc < 2; kc++)
                apA[kc] = *(const s16x8*)&Ps[wave][1][lm][(kc * 32 + quad * 8) ^ swz];
            #pragma unroll
            for (int t = 0; t < 4; t++)
                #pragma unroll
                for (int kc = 0; kc < 2; kc++) {
                    s16x8 bv = *(const s16x8*)&Vt[t * 16 + lm][(kc * 32 + quad * 8) ^ swz];
                    OB[t] = MFMA16(apB[kc], bv, OB[t]);
                    OA[t] = MFMA16(apA[kc], bv, OA[t]);
                }
        } else {
            #pragma unroll
            for (int t = 0; t < 4; t++)
                #pragma unroll
                for (int kc = 0; kc < 2; kc++) {
                    s16x8 bv = *(const s16x8*)&Vt[t * 16 + lm][(kc * 32 + quad * 8) ^ swz];
                    OB[t] = MFMA16(apB[kc], bv, OB[t]);
                }
        }
    }

    // ---- epilogue: O row q = wave*16+quad*4+r, col d = t*16+lm ----
    float liA[4], liB[4];
    #pragma unroll
    for (int r = 0; r < 4; r++) {
        liA[r] = 1.0f / __shfl(lA, quad * 4 + r, 64);
        liB[r] = 1.0f / __shfl(lB, quad * 4 + r, 64);
    }
    #pragma unroll
    for (int t = 0; t < 4; t++)
        #pragma unroll
        for (int r = 0; r < 4; r++) {
            int d  = t * 16 + lm;
            int qa = q0A + wave * 16 + quad * 4 + r;
            int qb = q0B + wave * 16 + quad * 4 + r;
            Yb[((size_t)b * T_ + qa) * C_ + h * D_ + d] =
                (short)f2b(OA[t][r] * liA[r]);
            Yb[((size_t)b * T_ + qb) * C_ + h * D_ + d] =
                (short)f2b(OB[t][r] * liB[r]);
        }
}

// ---------------------------------------------------------------------------
extern "C" void kernel_launch(void* const* d_in, const int* in_sizes, int n_in,
                              void* d_out, int out_size, void* d_ws, size_t ws_size,
                              hipStream_t stream)
{
    const float* x      = (const float*)d_in[0];
    const float* W_attn = (const float*)d_in[1];
    const float* b_attn = (const float*)d_in[2];
    const float* W_proj = (const float*)d_in[3];
    const float* b_proj = (const float*)d_in[4];
    float* out = (float*)d_out;

    char* ws = (char*)d_ws;
    const size_t MB = 1024 * 1024;
    short* Qh   = (short*)(ws);            // 8 MB  [ 0, 8)
    short* Ql   = (short*)(ws +  8 * MB);  // 8 MB  [ 8,16)
    short* Kh   = (short*)(ws + 16 * MB);  // 8 MB  [16,24)
    short* Kl   = (short*)(ws + 24 * MB);  // 8 MB  [24,32)
    short* xh   = (short*)(ws + 32 * MB);  // 8 MB  [32,40)  dead after qkv_v
    short* xl   = (short*)(ws + 40 * MB);  // 8 MB  [40,48)  dead after qkv_qk
    short* WaTh = (short*)(ws + 48 * MB);  // 6 MB  [48,54)
    short* WaTl = (short*)(ws + 54 * MB);  // 6 MB  [54,60)
    short* WpT  = (short*)(ws + 60 * MB);  // 2 MB  [60,62)
    short* VT   = (short*)(ws + 40 * MB);  // 8 MB  aliases xl (born at qkv_v)
    short* Yb   = (short*)(ws + 32 * MB);  // 8 MB  aliases xh (born at attn)

    cvt_split <<<dim3(M_ * C_ / 2048), 256, 0, stream>>>(x, xh, xl, M_ * C_);
    cvtT_split<<<dim3(N3_ / 64, C_ / 64), 256, 0, stream>>>(W_attn, WaTh, WaTl, C_, N3_);
    cvtT_bf16 <<<dim3(C_ / 64, C_ / 64), 256, 0, stream>>>(W_proj, WpT, C_, C_);

    qkv_qk <<<dim3(16, 64), 256, 0, stream>>>(xh, xl, WaTh, WaTl, b_attn,
                                              Qh, Ql, Kh, Kl);
    qkv_v  <<<dim3(8, 64), 256, 0, stream>>>(xh, WaTh + (size_t)2048 * C_,
                                             b_attn + 2048, VT);
    attn_mfma<<<dim3(512), 256, 0, stream>>>(Qh, Ql, Kh, Kl, VT, Yb);
    proj_mfma<<<dim3(8, 64), 256, 0, stream>>>(Yb, WpT, b_proj, out);
}

// Round 5
// 241.582 us; speedup vs baseline: 1.1099x; 1.0218x over previous
//
#include <hip/hip_runtime.h>
#include <hip/hip_bf16.h>

// Problem: CausalSelfAttention  B=2, T=2048, C=1024, H=16, D=64
// Round 17 (= R16 resubmit; container infra failure, no counters returned).
// LDS bank-conflict elimination in the GEMMs, zero structural change.
// R15 post-mortem: 64x128 qkv_qk is LDS-throughput-bound (12 b128/thread/kstep
// = 31us/CU of LDS time > 25us MFMA); 128^2 (R13, 68us) is the right balance
// (20.5us LDS < 24.8us MFMA). Restored. Remaining fixable cost: 8-way bank
// conflict on frag reads (4.19M cy = ~7us). Fix per G21: gload_lds keeps
// LINEAR LDS dest; the per-lane global SOURCE granule is XOR-permuted
// (gc = ((lane&3)^((lane>>3)&3))*8) and reads XOR the same key
// (col = (lq^((lm>>1)&3))*8). Each bank-quad then hit exactly 2x per
// 16-lane group = free (m136). Same swizzle in qkv_v/proj (kept 64x128).
// attn (paired q-tiles, XOR swizzle, defer-max) + cvt kernels unchanged.
// ws (62 MB): Qh 8|Ql 8|Kh 8|Kl 8|xh 8(->Yb)|xl 8(->VT)|WaTh 6|WaTl 6|WpT 2

#define B_  2
#define T_  2048
#define C_  1024
#define H_  16
#define D_  64
#define M_  (B_ * T_)      // 4096
#define N3_ (3 * C_)       // 3072

typedef __attribute__((ext_vector_type(8))) short s16x8;
typedef __attribute__((ext_vector_type(4))) short s16x4;
typedef __attribute__((ext_vector_type(4))) float f32x4;

typedef const __attribute__((address_space(1))) unsigned int gu32_t;
typedef __attribute__((address_space(3))) unsigned int lu32_t;

#define MFMA16(a, b, c) __builtin_amdgcn_mfma_f32_16x16x32_bf16(a, b, c, 0, 0, 0)

__device__ __forceinline__ void gload_lds16(const short* g, short* l) {
    __builtin_amdgcn_global_load_lds((gu32_t*)g, (lu32_t*)l, 16, 0, 0);
}

__device__ __forceinline__ float b2f(unsigned short u) {
    return __uint_as_float(((unsigned)u) << 16);
}
__device__ __forceinline__ unsigned short f2b(float f) {   // RNE bf16 round
    unsigned u = __float_as_uint(f);
    return (unsigned short)((u + 0x7FFFu + ((u >> 16) & 1u)) >> 16);
}
__device__ __forceinline__ float fexp2(float x) {
#if __has_builtin(__builtin_amdgcn_exp2f)
    return __builtin_amdgcn_exp2f(x);
#else
    return exp2f(x);
#endif
}

// ---------------------------------------------------------------------------
// fp32 -> (hi, lo) bf16 split. n multiple of 2048.
// ---------------------------------------------------------------------------
__global__ __launch_bounds__(256) void cvt_split(
    const float* __restrict__ in, short* __restrict__ oh, short* __restrict__ ol, int n)
{
    int i = (blockIdx.x * 256 + threadIdx.x) * 8;
    if (i >= n) return;
    float4 a = *(const float4*)&in[i];
    float4 b = *(const float4*)&in[i + 4];
    float v[8] = {a.x, a.y, a.z, a.w, b.x, b.y, b.z, b.w};
    s16x8 h, l;
    #pragma unroll
    for (int j = 0; j < 8; j++) {
        unsigned short hb = f2b(v[j]);
        h[j] = (short)hb;
        l[j] = (short)f2b(v[j] - b2f(hb));
    }
    *(s16x8*)&oh[i] = h;
    *(s16x8*)&ol[i] = l;
}

// ---------------------------------------------------------------------------
// fp32 [R,Cn] -> (hi,lo) bf16 [Cn,R] transpose+split. grid (Cn/64, R/64).
// ---------------------------------------------------------------------------
__global__ __launch_bounds__(256) void cvtT_split(
    const float* __restrict__ in, short* __restrict__ oh, short* __restrict__ ol,
    int R, int Cn)
{
    __shared__ short th[64][80];
    __shared__ short tl[64][80];
    const int tid = threadIdx.x;
    const int k0 = blockIdx.y * 64;
    const int n0 = blockIdx.x * 64;
    {
        int rl = tid >> 4, cl = (tid & 15) * 4;
        #pragma unroll
        for (int i = 0; i < 4; i++) {
            int kr = rl + i * 16;
            float4 v4 = *(const float4*)&in[(size_t)(k0 + kr) * Cn + n0 + cl];
            float v[4] = {v4.x, v4.y, v4.z, v4.w};
            #pragma unroll
            for (int j = 0; j < 4; j++) {
                unsigned short hb = f2b(v[j]);
                th[cl + j][kr] = (short)hb;
                tl[cl + j][kr] = (short)f2b(v[j] - b2f(hb));
            }
        }
    }
    __syncthreads();
    {
        int ro = tid >> 2, co = (tid & 3) * 16;
        *(s16x8*)&oh[(size_t)(n0 + ro) * R + k0 + co]     = *(s16x8*)&th[ro][co];
        *(s16x8*)&oh[(size_t)(n0 + ro) * R + k0 + co + 8] = *(s16x8*)&th[ro][co + 8];
        *(s16x8*)&ol[(size_t)(n0 + ro) * R + k0 + co]     = *(s16x8*)&tl[ro][co];
        *(s16x8*)&ol[(size_t)(n0 + ro) * R + k0 + co + 8] = *(s16x8*)&tl[ro][co + 8];
    }
}

// ---------------------------------------------------------------------------
// fp32 [R,Cn] -> bf16 [Cn,R] transpose (single, for W_proj).
// ---------------------------------------------------------------------------
__global__ __launch_bounds__(256) void cvtT_bf16(
    const float* __restrict__ in, short* __restrict__ out, int R, int Cn)
{
    __shared__ short t[64][80];
    const int tid = threadIdx.x;
    const int k0 = blockIdx.y * 64;
    const int n0 = blockIdx.x * 64;
    {
        int rl = tid >> 4, cl = (tid & 15) * 4;
        #pragma unroll
        for (int i = 0; i < 4; i++) {
            int kr = rl + i * 16;
            float4 v = *(const float4*)&in[(size_t)(k0 + kr) * Cn + n0 + cl];
            t[cl + 0][kr] = (short)f2b(v.x);
            t[cl + 1][kr] = (short)f2b(v.y);
            t[cl + 2][kr] = (short)f2b(v.z);
            t[cl + 3][kr] = (short)f2b(v.w);
        }
    }
    __syncthreads();
    {
        int ro = tid >> 2, co = (tid & 3) * 16;
        *(s16x8*)&out[(size_t)(n0 + ro) * R + k0 + co]     = *(s16x8*)&t[ro][co];
        *(s16x8*)&out[(size_t)(n0 + ro) * R + k0 + co + 8] = *(s16x8*)&t[ro][co + 8];
    }
}

// ---------------------------------------------------------------------------
// qkv_qk: Q,K columns (N=2048), bf16x3, hi/lo scatter. Q pre-scaled by
// 8*log2(e). 128x128 tile (R13 geometry), grid (16,32). LDS 32 KB.
// Bank-conflict-free via source-permute + read-XOR granule swizzle.
// ---------------------------------------------------------------------------
__global__ __launch_bounds__(256) void qkv_qk(
    const short* __restrict__ Ah, const short* __restrict__ Al,
    const short* __restrict__ BTh, const short* __restrict__ BTl,
    const float* __restrict__ bias,
    short* __restrict__ Qh, short* __restrict__ Ql,
    short* __restrict__ Kh, short* __restrict__ Kl)
{
    __shared__ short Ash[128 * 32], Asl[128 * 32];
    __shared__ short Bsh[128 * 32], Bsl[128 * 32];

    const int tid  = threadIdx.x;
    const int wave = tid >> 6, lane = tid & 63;
    const int wm = wave >> 1, wn = wave & 1;
    const int lm = lane & 15, lq = lane >> 4;
    const int m0 = blockIdx.y * 128, n0 = blockIdx.x * 128;
    const int gr  = (lane >> 2);
    // swizzled SOURCE granule: slot (row,g) holds global granule g^((row>>1)&3)
    const int gc  = (((lane & 3) ^ ((lane >> 3) & 3)) << 3);
    // swizzled READ col: logical granule lq of row-in-seg lm lives at lq^((lm>>1)&3)
    const int sg  = ((lq ^ ((lm >> 1) & 3)) << 3);

    f32x4 acc[4][4] = {};

    for (int k0 = 0; k0 < C_; k0 += 32) {
        __syncthreads();
        #pragma unroll
        for (int j = 0; j < 2; j++) {
            int s = wave * 2 + j;
            int row = s * 16 + gr;
            size_t ga = (size_t)(m0 + row) * C_ + k0 + gc;
            size_t gb = (size_t)(n0 + row) * C_ + k0 + gc;
            gload_lds16(&Ah[ga],  &Ash[s * 512]);
            gload_lds16(&Al[ga],  &Asl[s * 512]);
            gload_lds16(&BTh[gb], &Bsh[s * 512]);
            gload_lds16(&BTl[gb], &Bsl[s * 512]);
        }
        __syncthreads();

        s16x8 ah[4], al[4], bh[4], bl[4];
        #pragma unroll
        for (int mi = 0; mi < 4; mi++) {
            int r = wm * 64 + mi * 16 + lm;
            ah[mi] = *(const s16x8*)&Ash[r * 32 + sg];
            al[mi] = *(const s16x8*)&Asl[r * 32 + sg];
        }
        #pragma unroll
        for (int nj = 0; nj < 4; nj++) {
            int r = wn * 64 + nj * 16 + lm;
            bh[nj] = *(const s16x8*)&Bsh[r * 32 + sg];
            bl[nj] = *(const s16x8*)&Bsl[r * 32 + sg];
        }
        #pragma unroll
        for (int mi = 0; mi < 4; mi++)
            #pragma unroll
            for (int nj = 0; nj < 4; nj++) {
                acc[mi][nj] = MFMA16(ah[mi], bh[nj], acc[mi][nj]);
                acc[mi][nj] = MFMA16(ah[mi], bl[nj], acc[mi][nj]);
                acc[mi][nj] = MFMA16(al[mi], bh[nj], acc[mi][nj]);
            }
    }

    #pragma unroll
    for (int nj = 0; nj < 4; nj++) {
        int n = n0 + wn * 64 + nj * 16 + lm;
        float bv = bias[n];
        int isK = n >> 10;
        int c = n & (C_ - 1);
        int h = c >> 6, d = c & (D_ - 1);
        short* dh = isK ? Kh : Qh;
        short* dl = isK ? Kl : Ql;
        // Q carries sqrt(D)=8 and log2(e): softmax runs in exp2 domain
        float scale = isK ? 1.0f : 11.541560327111708f;   // 8*log2(e)
        #pragma unroll
        for (int mi = 0; mi < 4; mi++) {
            #pragma unroll
            for (int r = 0; r < 4; r++) {
                int m  = m0 + wm * 64 + mi * 16 + lq * 4 + r;
                int bb = m >> 11, t = m & (T_ - 1);
                float v = (acc[mi][nj][r] + bv) * scale;
                size_t idx = (((size_t)bb * H_ + h) * T_ + t) * D_ + d;
                unsigned short hb = f2b(v);
                dh[idx] = (short)hb;
                dl[idx] = (short)f2b(v - b2f(hb));
            }
        }
    }
}

// ---------------------------------------------------------------------------
// qkv_v: V columns (N=1024), single bf16, scatter TRANSPOSED -> VT [B,H,D,T].
// 64x128 tile, grid (8,64) = 512 blocks. Swizzled LDS.
// ---------------------------------------------------------------------------
__global__ __launch_bounds__(256, 4) void qkv_v(
    const short* __restrict__ Ah, const short* __restrict__ BTh,
    const float* __restrict__ bias, short* __restrict__ VT)
{
    __shared__ short Ash[64 * 32];    // 4 KB
    __shared__ short Bsh[128 * 32];   // 8 KB

    const int tid  = threadIdx.x;
    const int wave = tid >> 6, lane = tid & 63;
    const int wm = wave >> 1, wn = wave & 1;
    const int lm = lane & 15, lq = lane >> 4;
    const int m0 = blockIdx.y * 64, n0 = blockIdx.x * 128;
    const int gr  = (lane >> 2);
    const int gc  = (((lane & 3) ^ ((lane >> 3) & 3)) << 3);
    const int sg  = ((lq ^ ((lm >> 1) & 3)) << 3);

    f32x4 acc[2][4] = {};

    for (int k0 = 0; k0 < C_; k0 += 32) {
        __syncthreads();
        {
            int rowA = wave * 16 + gr;
            gload_lds16(&Ah[(size_t)(m0 + rowA) * C_ + k0 + gc], &Ash[wave * 512]);
            #pragma unroll
            for (int j = 0; j < 2; j++) {
                int s = wave * 2 + j;
                int rowB = s * 16 + gr;
                gload_lds16(&BTh[(size_t)(n0 + rowB) * C_ + k0 + gc], &Bsh[s * 512]);
            }
        }
        __syncthreads();

        s16x8 af[2], bfr[4];
        #pragma unroll
        for (int mi = 0; mi < 2; mi++)
            af[mi] = *(const s16x8*)&Ash[(wm * 32 + mi * 16 + lm) * 32 + sg];
        #pragma unroll
        for (int nj = 0; nj < 4; nj++)
            bfr[nj] = *(const s16x8*)&Bsh[(wn * 64 + nj * 16 + lm) * 32 + sg];
        #pragma unroll
        for (int mi = 0; mi < 2; mi++)
            #pragma unroll
            for (int nj = 0; nj < 4; nj++)
                acc[mi][nj] = MFMA16(af[mi], bfr[nj], acc[mi][nj]);
    }

    #pragma unroll
    for (int nj = 0; nj < 4; nj++) {
        int n = n0 + wn * 64 + nj * 16 + lm;    // [0, 1024) V channel
        float bv = bias[n];
        int h = n >> 6, d = n & (D_ - 1);
        #pragma unroll
        for (int mi = 0; mi < 2; mi++) {
            #pragma unroll
            for (int r = 0; r < 4; r++) {
                int m  = m0 + wm * 32 + mi * 16 + lq * 4 + r;
                int bb = m >> 11, t = m & (T_ - 1);
                VT[(((size_t)bb * H_ + h) * D_ + d) * T_ + t] =
                    (short)f2b(acc[mi][nj][r] + bv);
            }
        }
    }
}

// ---------------------------------------------------------------------------
// proj: out fp32 [M,C] = Yb(bf16) @ WpT(bf16) + bias. 64x128 tile, grid 512.
// Swizzled LDS.
// ---------------------------------------------------------------------------
__global__ __launch_bounds__(256, 4) void proj_mfma(
    const short* __restrict__ Ah, const short* __restrict__ BTh,
    const float* __restrict__ bias, float* __restrict__ out)
{
    __shared__ short Ash[64 * 32];
    __shared__ short Bsh[128 * 32];

    const int tid  = threadIdx.x;
    const int wave = tid >> 6, lane = tid & 63;
    const int wm = wave >> 1, wn = wave & 1;
    const int lm = lane & 15, lq = lane >> 4;
    const int m0 = blockIdx.y * 64, n0 = blockIdx.x * 128;
    const int gr  = (lane >> 2);
    const int gc  = (((lane & 3) ^ ((lane >> 3) & 3)) << 3);
    const int sg  = ((lq ^ ((lm >> 1) & 3)) << 3);

    f32x4 acc[2][4] = {};

    for (int k0 = 0; k0 < C_; k0 += 32) {
        __syncthreads();
        {
            int rowA = wave * 16 + gr;
            gload_lds16(&Ah[(size_t)(m0 + rowA) * C_ + k0 + gc], &Ash[wave * 512]);
            #pragma unroll
            for (int j = 0; j < 2; j++) {
                int s = wave * 2 + j;
                int rowB = s * 16 + gr;
                gload_lds16(&BTh[(size_t)(n0 + rowB) * C_ + k0 + gc], &Bsh[s * 512]);
            }
        }
        __syncthreads();

        s16x8 af[2], bfr[4];
        #pragma unroll
        for (int mi = 0; mi < 2; mi++)
            af[mi] = *(const s16x8*)&Ash[(wm * 32 + mi * 16 + lm) * 32 + sg];
        #pragma unroll
        for (int nj = 0; nj < 4; nj++)
            bfr[nj] = *(const s16x8*)&Bsh[(wn * 64 + nj * 16 + lm) * 32 + sg];
        #pragma unroll
        for (int mi = 0; mi < 2; mi++)
            #pragma unroll
            for (int nj = 0; nj < 4; nj++)
                acc[mi][nj] = MFMA16(af[mi], bfr[nj], acc[mi][nj]);
    }

    #pragma unroll
    for (int nj = 0; nj < 4; nj++) {
        int n = n0 + wn * 64 + nj * 16 + lm;
        float bv = bias[n];
        #pragma unroll
        for (int mi = 0; mi < 2; mi++) {
            #pragma unroll
            for (int r = 0; r < 4; r++) {
                int m = m0 + wm * 32 + mi * 16 + lq * 4 + r;
                out[(size_t)m * C_ + n] = acc[mi][nj][r] + bv;
            }
        }
    }
}

// ---------------------------------------------------------------------------
// online softmax (exp2 domain) with defer-max (THR=8). S in/out: S^T frag,
// per-thread 16 values for q-row lm. On exit S holds P = exp2(S - m).
// ---------------------------------------------------------------------------
__device__ __forceinline__ void online_sm(
    f32x4 S[4], float& mrow, float& lrow, f32x4 O[4], int quad)
{
    float v[16];
    #pragma unroll
    for (int t = 0; t < 4; t++)
        #pragma unroll
        for (int r = 0; r < 4; r++) v[t * 4 + r] = S[t][r];
    #pragma unroll
    for (int s = 8; s; s >>= 1)
        #pragma unroll
        for (int i = 0; i < s; i++) v[i] = fmaxf(v[i], v[i + s]);
    float rm = v[0];
    rm = fmaxf(rm, __shfl_xor(rm, 16, 64));
    rm = fmaxf(rm, __shfl_xor(rm, 32, 64));
    // defer-max: only rescale when some row grew by > 8 (=2^8 headroom)
    if (!__all(rm - mrow <= 8.f)) {
        float mnew  = fmaxf(mrow, rm);
        float alpha = fexp2(mrow - mnew);
        mrow = mnew;
        lrow *= alpha;
        float al[4];
        #pragma unroll
        for (int r = 0; r < 4; r++) al[r] = __shfl(alpha, quad * 4 + r, 64);
        #pragma unroll
        for (int t = 0; t < 4; t++)
            #pragma unroll
            for (int r = 0; r < 4; r++) O[t][r] *= al[r];
    }
    float sv[16];
    #pragma unroll
    for (int t = 0; t < 4; t++)
        #pragma unroll
        for (int r = 0; r < 4; r++) {
            float p = fexp2(S[t][r] - mrow);
            S[t][r] = p;
            sv[t * 4 + r] = p;
        }
    #pragma unroll
    for (int s = 8; s; s >>= 1)
        #pragma unroll
        for (int i = 0; i < s; i++) sv[i] += sv[i + s];
    float rs = sv[0];
    rs += __shfl_xor(rs, 16, 64);
    rs += __shfl_xor(rs, 32, 64);
    lrow += rs;
}

// ---------------------------------------------------------------------------
// MFMA flash attention, S^T layout, PAIRED q-tiles per block. Grid 512.
// Block handles qtA=j (j in 0..15) and qtB=31-j of one (b,h): exactly 33
// compute-units each. K/V staged once per kt, shared by both tiles; for
// kt<=j one LDS k-frag read feeds 6 MFMAs (dual chains = intra-wave ILP).
// Slot map pairs j with 15-j -> per-CU iteration count 49 (constant).
// LDS 40KB, XOR-swizzled [64][64] (conflict-free), 2 blocks/CU.
// Q pre-scaled by 8*log2e; softmax exp2-domain with defer-max.
// ---------------------------------------------------------------------------
__global__ __launch_bounds__(256, 2) void attn_mfma(
    const short* __restrict__ Qh, const short* __restrict__ Ql,
    const short* __restrict__ Kh, const short* __restrict__ Kl,
    const short* __restrict__ VT, short* __restrict__ Yb)
{
    __shared__ short Ksh[64][64], Ksl[64][64];   // [key][d], XOR-swizzled
    __shared__ short Vt [64][64];                // [d][key], XOR-swizzled
    __shared__ short Ps [4][2][16][64];          // per-wave P slabs (B=0,A=1)

    const int tid  = threadIdx.x;
    const int wave = tid >> 6, lane = tid & 63;
    const int lm   = lane & 15, quad = lane >> 4;
    const int swz  = (lm & 7) << 3;              // read-side XOR (shorts)

    const int bid = blockIdx.x;                  // 512 blocks
    const int xcd = bid & 7;
    const int r_  = bid >> 3;                    // 0..63 per XCD
    const int bhl = r_ & 3;
    const int u   = r_ >> 2;                     // 0..15
    const int g_  = u >> 3, j_ = u & 7;
    const int j   = g_ ? (15 - j_) : j_;         // CU slot pairs j with 15-j
    const int bh  = xcd * 4 + bhl;
    const int b   = bh >> 4, h = bh & (H_ - 1);
    const int qtA = j, qtB = 31 - j;
    const int q0A = qtA * 64, q0B = qtB * 64;
    const size_t base  = (size_t)bh * T_ * D_;   // Q,K: [b,h,t,d]
    const size_t vbase = (size_t)bh * D_ * T_;   // VT:  [b,h,d,t]

    const int src = tid >> 3;                    // staging row 0..31 (+32)
    const int sch = (tid & 7) * 8;               // linear global col (shorts)
    const int wsw = sch ^ ((src & 7) << 3);      // swizzled LDS write col

    // ---- Q frags direct from global (L2-hit, once per block) ----
    s16x8 bqhA[2], bqlA[2], bqhB[2], bqlB[2];
    #pragma unroll
    for (int kc = 0; kc < 2; kc++) {
        size_t ga = base + (size_t)(q0A + wave * 16 + lm) * D_ + kc * 32 + quad * 8;
        size_t gb = base + (size_t)(q0B + wave * 16 + lm) * D_ + kc * 32 + quad * 8;
        bqhA[kc] = *(const s16x8*)&Qh[ga];
        bqlA[kc] = *(const s16x8*)&Ql[ga];
        bqhB[kc] = *(const s16x8*)&Qh[gb];
        bqlB[kc] = *(const s16x8*)&Ql[gb];
    }

    // ---- prefetch k-tile 0 into registers ----
    s16x8 pkh[2], pkl[2], pvt[2];
    #pragma unroll
    for (int i = 0; i < 2; i++) {
        int row = i * 32 + src;
        size_t gk = base + (size_t)row * D_ + sch;
        pkh[i] = *(const s16x8*)&Kh[gk];
        pkl[i] = *(const s16x8*)&Kl[gk];
        pvt[i] = *(const s16x8*)&VT[vbase + (size_t)row * T_ + sch];
    }

    float mA = -INFINITY, lA = 0.f;
    float mB = -INFINITY, lB = 0.f;
    f32x4 OA[4] = {}, OB[4] = {};

    for (int kt = 0; kt <= qtB; kt++) {
        __syncthreads();                          // prev tile's readers done
        #pragma unroll
        for (int i = 0; i < 2; i++) {             // VGPR -> LDS (swizzled)
            int row = i * 32 + src;
            *(s16x8*)&Ksh[row][wsw] = pkh[i];
            *(s16x8*)&Ksl[row][wsw] = pkl[i];
            *(s16x8*)&Vt [row][wsw] = pvt[i];
        }
        if (kt < qtB) {                           // issue next tile's loads
            #pragma unroll
            for (int i = 0; i < 2; i++) {
                int row = i * 32 + src;
                size_t gk = base + (size_t)((kt + 1) * 64 + row) * D_ + sch;
                pkh[i] = *(const s16x8*)&Kh[gk];
                pkl[i] = *(const s16x8*)&Kl[gk];
                pvt[i] = *(const s16x8*)&VT[vbase + (size_t)row * T_ + (kt + 1) * 64 + sch];
            }
        }
        __syncthreads();

        const bool doA = (kt <= qtA);
        const int  qg  = wave * 16 + lm;

        f32x4 SB[4] = {}, SA[4] = {};
        if (doA) {
            // dual: one k-frag read feeds 6 MFMAs (two independent chains)
            #pragma unroll
            for (int t = 0; t < 4; t++)
                #pragma unroll
                for (int kc = 0; kc < 2; kc++) {
                    s16x8 kh8 = *(const s16x8*)&Ksh[t * 16 + lm][(kc * 32 + quad * 8) ^ swz];
                    s16x8 kl8 = *(const s16x8*)&Ksl[t * 16 + lm][(kc * 32 + quad * 8) ^ swz];
                    SB[t] = MFMA16(kh8, bqhB[kc], SB[t]);
                    SB[t] = MFMA16(kl8, bqhB[kc], SB[t]);
                    SB[t] = MFMA16(kh8, bqlB[kc], SB[t]);
                    SA[t] = MFMA16(kh8, bqhA[kc], SA[t]);
                    SA[t] = MFMA16(kl8, bqhA[kc], SA[t]);
                    SA[t] = MFMA16(kh8, bqlA[kc], SA[t]);
                }
        } else {
            #pragma unroll
            for (int t = 0; t < 4; t++)
                #pragma unroll
                for (int kc = 0; kc < 2; kc++) {
                    s16x8 kh8 = *(const s16x8*)&Ksh[t * 16 + lm][(kc * 32 + quad * 8) ^ swz];
                    s16x8 kl8 = *(const s16x8*)&Ksl[t * 16 + lm][(kc * 32 + quad * 8) ^ swz];
                    SB[t] = MFMA16(kh8, bqhB[kc], SB[t]);
                    SB[t] = MFMA16(kl8, bqhB[kc], SB[t]);
                    SB[t] = MFMA16(kh8, bqlB[kc], SB[t]);
                }
        }

        // causal masks (scale pre-folded into Q)
        if (kt == qtB) {
            #pragma unroll
            for (int t = 0; t < 4; t++)
                #pragma unroll
                for (int r = 0; r < 4; r++)
                    if ((t * 16 + quad * 4 + r) > qg) SB[t][r] = -INFINITY;
        }
        if (kt == qtA) {
            #pragma unroll
            for (int t = 0; t < 4; t++)
                #pragma unroll
                for (int r = 0; r < 4; r++)
                    if ((t * 16 + quad * 4 + r) > qg) SA[t][r] = -INFINITY;
        }

        // ---- softmax (dual chains are independent) ----
        online_sm(SB, mB, lB, OB, quad);
        if (doA) online_sm(SA, mA, lA, OA, quad);

        // ---- P^T -> Ps (truncating bf16; P in [0, 256]) ----
        #pragma unroll
        for (int t = 0; t < 4; t++) {
            s16x4 p;
            #pragma unroll
            for (int r = 0; r < 4; r++)
                p[r] = (short)(__float_as_uint(SB[t][r]) >> 16);
            *(s16x4*)&Ps[wave][0][lm][(t * 16 + quad * 4) ^ swz] = p;
        }
        if (doA) {
            #pragma unroll
            for (int t = 0; t < 4; t++) {
                s16x4 p;
                #pragma unroll
                for (int r = 0; r < 4; r++)
                    p[r] = (short)(__float_as_uint(SA[t][r]) >> 16);
                *(s16x4*)&Ps[wave][1][lm][(t * 16 + quad * 4) ^ swz] = p;
            }
        }
        // wave-private slabs: no barrier (lgkmcnt ordering within wave)

        // ---- O += P V: shared Vt frag feeds both tiles ----
        s16x8 apB[2], apA[2];
        #pragma unroll
        for (int kc = 0; kc < 2; kc++)
            apB[kc] = *(const s16x8*)&Ps[wave][0][lm][(kc * 32 + quad * 8) ^ swz];
        if (doA) {
            #pragma unroll
            for (int kc = 0; kc < 2; kc++)
                apA[kc] = *(const s16x8*)&Ps[wave][1][lm][(kc * 32 + quad * 8) ^ swz];
            #pragma unroll
            for (int t = 0; t < 4; t++)
                #pragma unroll
                for (int kc = 0; kc < 2; kc++) {
                    s16x8 bv = *(const s16x8*)&Vt[t * 16 + lm][(kc * 32 + quad * 8) ^ swz];
                    OB[t] = MFMA16(apB[kc], bv, OB[t]);
                    OA[t] = MFMA16(apA[kc], bv, OA[t]);
                }
        } else {
            #pragma unroll
            for (int t = 0; t < 4; t++)
                #pragma unroll
                for (int kc = 0; kc < 2; kc++) {
                    s16x8 bv = *(const s16x8*)&Vt[t * 16 + lm][(kc * 32 + quad * 8) ^ swz];
                    OB[t] = MFMA16(apB[kc], bv, OB[t]);
                }
        }
    }

    // ---- epilogue: O row q = wave*16+quad*4+r, col d = t*16+lm ----
    float liA[4], liB[4];
    #pragma unroll
    for (int r = 0; r < 4; r++) {
        liA[r] = 1.0f / __shfl(lA, quad * 4 + r, 64);
        liB[r] = 1.0f / __shfl(lB, quad * 4 + r, 64);
    }
    #pragma unroll
    for (int t = 0; t < 4; t++)
        #pragma unroll
        for (int r = 0; r < 4; r++) {
            int d  = t * 16 + lm;
            int qa = q0A + wave * 16 + quad * 4 + r;
            int qb = q0B + wave * 16 + quad * 4 + r;
            Yb[((size_t)b * T_ + qa) * C_ + h * D_ + d] =
                (short)f2b(OA[t][r] * liA[r]);
            Yb[((size_t)b * T_ + qb) * C_ + h * D_ + d] =
                (short)f2b(OB[t][r] * liB[r]);
        }
}

// ---------------------------------------------------------------------------
extern "C" void kernel_launch(void* const* d_in, const int* in_sizes, int n_in,
                              void* d_out, int out_size, void* d_ws, size_t ws_size,
                              hipStream_t stream)
{
    const float* x      = (const float*)d_in[0];
    const float* W_attn = (const float*)d_in[1];
    const float* b_attn = (const float*)d_in[2];
    const float* W_proj = (const float*)d_in[3];
    const float* b_proj = (const float*)d_in[4];
    float* out = (float*)d_out;

    char* ws = (char*)d_ws;
    const size_t MB = 1024 * 1024;
    short* Qh   = (short*)(ws);            // 8 MB  [ 0, 8)
    short* Ql   = (short*)(ws +  8 * MB);  // 8 MB  [ 8,16)
    short* Kh   = (short*)(ws + 16 * MB);  // 8 MB  [16,24)
    short* Kl   = (short*)(ws + 24 * MB);  // 8 MB  [24,32)
    short* xh   = (short*)(ws + 32 * MB);  // 8 MB  [32,40)  dead after qkv_v
    short* xl   = (short*)(ws + 40 * MB);  // 8 MB  [40,48)  dead after qkv_qk
    short* WaTh = (short*)(ws + 48 * MB);  // 6 MB  [48,54)
    short* WaTl = (short*)(ws + 54 * MB);  // 6 MB  [54,60)
    short* WpT  = (short*)(ws + 60 * MB);  // 2 MB  [60,62)
    short* VT   = (short*)(ws + 40 * MB);  // 8 MB  aliases xl (born at qkv_v)
    short* Yb   = (short*)(ws + 32 * MB);  // 8 MB  aliases xh (born at attn)

    cvt_split <<<dim3(M_ * C_ / 2048), 256, 0, stream>>>(x, xh, xl, M_ * C_);
    cvtT_split<<<dim3(N3_ / 64, C_ / 64), 256, 0, stream>>>(W_attn, WaTh, WaTl, C_, N3_);
    cvtT_bf16 <<<dim3(C_ / 64, C_ / 64), 256, 0, stream>>>(W_proj, WpT, C_, C_);

    qkv_qk <<<dim3(16, 32), 256, 0, stream>>>(xh, xl, WaTh, WaTl, b_attn,
                                              Qh, Ql, Kh, Kl);
    qkv_v  <<<dim3(8, 64), 256, 0, stream>>>(xh, WaTh + (size_t)2048 * C_,
                                             b_attn + 2048, VT);
    attn_mfma<<<dim3(512), 256, 0, stream>>>(Qh, Ql, Kh, Kl, VT, Yb);
    proj_mfma<<<dim3(8, 64), 256, 0, stream>>>(Yb, WpT, b_proj, out);
}